// Round 9
// baseline (319.365 us; speedup 1.0000x reference)
//
#include <hip/hip_runtime.h>

#define N_NODES 25000
#define N_EDGES 400000
#define IN_CH 1024
#define FC 128
#define ADD_CH 20
#define XCH 148   // FC + ADD
#define MID 37
#define OUT_CH 3
#define MAXDEG 64
#define CSTRIDE 16   // cursor padded to one counter per 64B line

typedef short bf16x8 __attribute__((ext_vector_type(8)));
typedef float f32x4 __attribute__((ext_vector_type(4)));

__device__ __forceinline__ float bflo(unsigned int v) {
    return __builtin_bit_cast(float, v << 16);
}
__device__ __forceinline__ float bfhi(unsigned int v) {
    return __builtin_bit_cast(float, v & 0xffff0000u);
}
// pack 2 f32 -> 2 bf16 (RNE), single VALU op
__device__ __forceinline__ unsigned int cvtpk(float a, float b) {
    unsigned int r;
    asm("v_cvt_pk_bf16_f32 %0, %1, %2" : "=v"(r) : "v"(a), "v"(b));
    return r;
}

// ---------------- prep: W swizzle + cursor zero (one dispatch) --------------
// Wpk layout: [kt(32)][chgrp(16)][lane(64)] x 16B; unit (kt,chgrp) lane (q,l15)
// holds W[chgrp*16+l15][kt*32+q*8 .. +8] as bf16x8. 512 KB total, L2-resident.
#define WSWZ_B 16
#define ZERO_B 49   // 49*512 >= 25000 (each thread zeroes one padded line)

__global__ __launch_bounds__(512) void prep(const float* __restrict__ Wl,
                                            const float* __restrict__ Wr,
                                            ushort* __restrict__ Wpk,
                                            int* __restrict__ cursor) {
    int b = blockIdx.x, t = threadIdx.x;
    if (b < WSWZ_B) {
        int w = t >> 6, lane = t & 63, l15 = lane & 15, q8 = (lane >> 4) * 8;
        int ch = b * 16 + l15;
        const float* src = (ch < FC) ? (Wl + (size_t)ch * IN_CH)
                                     : (Wr + (size_t)(ch - FC) * IN_CH);
        #pragma unroll
        for (int j = 0; j < 4; ++j) {
            int kt = w * 4 + j;
            float4 lo = *(const float4*)(src + kt * 32 + q8);
            float4 hi = *(const float4*)(src + kt * 32 + q8 + 4);
            uint4 pk;
            pk.x = cvtpk(lo.x, lo.y); pk.y = cvtpk(lo.z, lo.w);
            pk.z = cvtpk(hi.x, hi.y); pk.w = cvtpk(hi.z, hi.w);
            ((uint4*)Wpk)[((size_t)kt * 16 + b) * 64 + lane] = pk;
        }
    } else {
        int i = (b - WSWZ_B) * 512 + t;
        if (i < N_NODES) {
            uint4 z = {0, 0, 0, 0};
            uint4* dst = (uint4*)(cursor + (size_t)i * CSTRIDE);
            dst[0] = z; dst[1] = z; dst[2] = z; dst[3] = z;
        }
    }
}

// ---------------- hetero: BARRIER-FREE streaming GEMM + ILP build -----------
// Round-9 structural insight: this GEMM is 13 GFLOP (1.6us MFMA), A streamed
// ONCE (102 MB), W L2-resident (512 KB). There is no reuse for LDS to capture
// -- the LDS+barrier pipeline (R2-R8) imposed a ~20us ds_read_b128 throughput
// floor (128 b128/CU/chunk @ 12cy) plus barrier convoying. Delete it all:
// each wave streams W-frags (coalesced dwordx4, L2) and A-frags (32B/lane,
// adjacent chunks complete 64B lines) straight to registers, depth-2 queue,
// no __shared__, no barriers, no waitcnt choreography. TLP (4-5 waves/SIMD)
// plus the register queue hides L2/HBM latency without any convoy.
//   Block 256 thr = 4 waves; wave w = 32 nodes x 64 ch (chgrps w*4..w*4+3).
//   Per chunk/wave: 4 W dwordx4 + 4 A f32x4 + 8 cvtpk + 8 MFMA.
// Build rides along: 4 independent edge chains/thread (ILP over atomics).
#define GEMM_B 782    // ceil(25000/32)
#define BUILD_B 391   // ceil(400000/1024)

__global__ __launch_bounds__(256, 4) void gemm_build(const float* __restrict__ A,
                                                     const ushort* __restrict__ Wpk,
                                                     ushort* __restrict__ Py,
                                                     ushort* __restrict__ Pz,
                                                     const int* __restrict__ edges,
                                                     int* __restrict__ cursor,
                                                     int* __restrict__ col) {
    int b = blockIdx.x, t = threadIdx.x;
    if (b >= GEMM_B) {
        int base = (b - GEMM_B) * 1024 + t;
        int src[4], dst[4], pos[4];
        #pragma unroll
        for (int k = 0; k < 4; ++k) {
            int e = base + k * 256;
            bool v = (e < N_EDGES);
            dst[k] = v ? edges[N_EDGES + e] : 0;
            src[k] = v ? edges[e] : 0;
        }
        #pragma unroll
        for (int k = 0; k < 4; ++k) {
            int e = base + k * 256;
            if (e < N_EDGES)
                pos[k] = atomicAdd(&cursor[(size_t)dst[k] * CSTRIDE], 1);
        }
        #pragma unroll
        for (int k = 0; k < 4; ++k) {
            int e = base + k * 256;
            if (e < N_EDGES && pos[k] < MAXDEG)
                col[dst[k] * MAXDEG + pos[k]] = src[k];
        }
        return;
    }
    int m0 = b * 32;
    int w = t >> 6, lane = t & 63;
    int l15 = lane & 15, q = lane >> 4;

    int n0 = m0 + l15;      if (n0 >= N_NODES) n0 = N_NODES - 1;
    int n1 = m0 + 16 + l15; if (n1 >= N_NODES) n1 = N_NODES - 1;
    const float* A0 = A + (size_t)n0 * IN_CH + q * 8;
    const float* A1 = A + (size_t)n1 * IN_CH + q * 8;
    // W frag i of chunk kt: Wld[kt*1024 + i*64]
    const uint4* Wld = (const uint4*)Wpk + (size_t)(w * 4) * 64 + lane;

    f32x4 acc[4][2] = {};

    uint4 wq0, wq1, wq2, wq3;         // next-chunk W queue
    f32x4 aq0, aq1, aq2, aq3;         // next-chunk A queue (f32)
    #define LDW(kt) { const uint4* p = Wld + (size_t)(kt) * 1024;                  \
                      wq0 = p[0]; wq1 = p[64]; wq2 = p[128]; wq3 = p[192]; }
    #define LDA(kt) { aq0 = *(const f32x4*)(A0 + (kt) * 32);                       \
                      aq1 = *(const f32x4*)(A0 + (kt) * 32 + 4);                   \
                      aq2 = *(const f32x4*)(A1 + (kt) * 32);                       \
                      aq3 = *(const f32x4*)(A1 + (kt) * 32 + 4); }
    LDW(0)
    LDA(0)
    #pragma unroll
    for (int kt = 0; kt < 32; ++kt) {
        uint4 wc0 = wq0, wc1 = wq1, wc2 = wq2, wc3 = wq3;
        f32x4 ac0 = aq0, ac1 = aq1, ac2 = aq2, ac3 = aq3;
        if (kt + 1 < 32) {            // issue next chunk before using current
            LDW(kt + 1)
            LDA(kt + 1)
        }
        uint4 p0, p1;
        p0.x = cvtpk(ac0[0], ac0[1]); p0.y = cvtpk(ac0[2], ac0[3]);
        p0.z = cvtpk(ac1[0], ac1[1]); p0.w = cvtpk(ac1[2], ac1[3]);
        p1.x = cvtpk(ac2[0], ac2[1]); p1.y = cvtpk(ac2[2], ac2[3]);
        p1.z = cvtpk(ac3[0], ac3[1]); p1.w = cvtpk(ac3[2], ac3[3]);
        bf16x8 af0 = __builtin_bit_cast(bf16x8, p0);
        bf16x8 af1 = __builtin_bit_cast(bf16x8, p1);
        bf16x8 wf0 = __builtin_bit_cast(bf16x8, wc0);
        bf16x8 wf1 = __builtin_bit_cast(bf16x8, wc1);
        bf16x8 wf2 = __builtin_bit_cast(bf16x8, wc2);
        bf16x8 wf3 = __builtin_bit_cast(bf16x8, wc3);
        acc[0][0] = __builtin_amdgcn_mfma_f32_16x16x32_bf16(wf0, af0, acc[0][0], 0, 0, 0);
        acc[0][1] = __builtin_amdgcn_mfma_f32_16x16x32_bf16(wf0, af1, acc[0][1], 0, 0, 0);
        acc[1][0] = __builtin_amdgcn_mfma_f32_16x16x32_bf16(wf1, af0, acc[1][0], 0, 0, 0);
        acc[1][1] = __builtin_amdgcn_mfma_f32_16x16x32_bf16(wf1, af1, acc[1][1], 0, 0, 0);
        acc[2][0] = __builtin_amdgcn_mfma_f32_16x16x32_bf16(wf2, af0, acc[2][0], 0, 0, 0);
        acc[2][1] = __builtin_amdgcn_mfma_f32_16x16x32_bf16(wf2, af1, acc[2][1], 0, 0, 0);
        acc[3][0] = __builtin_amdgcn_mfma_f32_16x16x32_bf16(wf3, af0, acc[3][0], 0, 0, 0);
        acc[3][1] = __builtin_amdgcn_mfma_f32_16x16x32_bf16(wf3, af1, acc[3][1], 0, 0, 0);
    }
    #undef LDW
    #undef LDA

    // D layout: ch = w*64 + i*16 + q*4 + reg, node = m0 + g2*16 + l15
    #pragma unroll
    for (int g2 = 0; g2 < 2; ++g2) {
        int node = m0 + g2 * 16 + l15;
        if (node < N_NODES) {
            ushort* base = (w < 2) ? (Py + (size_t)node * FC + (w & 1) * 64 + q * 4)
                                   : (Pz + (size_t)node * FC + (w & 1) * 64 + q * 4);
            #pragma unroll
            for (int i = 0; i < 4; ++i) {
                f32x4 v = acc[i][g2];
                uint2 pk;
                pk.x = cvtpk(v[0], v[1]);
                pk.y = cvtpk(v[2], v[3]);
                *(uint2*)(base + i * 16) = pk;
            }
        }
    }
}

// ---------------- fused gather + SAGE combine + MLP tail (8 nodes/block) ----
__global__ __launch_bounds__(512) void fused_tail(const ushort* __restrict__ Py,
                                                  const ushort* __restrict__ Pz,
                                                  const int* __restrict__ deg,
                                                  const int* __restrict__ col,
                                                  const float* __restrict__ addf,
                                                  const float* __restrict__ bl,
                                                  const float* __restrict__ W1,
                                                  const float* __restrict__ b1,
                                                  const float* __restrict__ W2,
                                                  const float* __restrict__ b2,
                                                  const float* __restrict__ gamma,
                                                  const float* __restrict__ beta,
                                                  const float* __restrict__ rmean,
                                                  const float* __restrict__ rvar,
                                                  float* __restrict__ out) {
    __shared__ float W1s[XCH][MID + 3];
    __shared__ float xbuf[8][XCH + 4];
    __shared__ float hbuf[8][MID + 3];
    int t = threadIdx.x;
    for (int idx = t; idx < MID * XCH; idx += 512) {
        int j = idx / XCH, k = idx - j * XCH;
        W1s[k][j] = W1[idx];
    }
    __syncthreads();
    int w = t >> 6, lane = t & 63;
    int n = blockIdx.x * 8 + w;
    bool valid = (n < N_NODES);
    int d = valid ? deg[(size_t)n * CSTRIDE] : 0;
    if (d > MAXDEG) d = MAXDEG;
    int g = lane >> 4, c16 = lane & 15;
    float s[8] = {0.f, 0.f, 0.f, 0.f, 0.f, 0.f, 0.f, 0.f};
    if (d > 0) {
        int cidx = col[n * MAXDEG + (lane < d ? lane : 0)];
        for (int i = 0; i < d; i += 16) {
            int e[4];
            uint4 v[4];
            #pragma unroll
            for (int j = 0; j < 4; ++j) {
                int ee = i + g + j * 4;
                e[j] = __shfl(cidx, (ee < d) ? ee : 0);
            }
            #pragma unroll
            for (int j = 0; j < 4; ++j)
                v[j] = *(const uint4*)&Py[(size_t)e[j] * FC + c16 * 8];
            #pragma unroll
            for (int j = 0; j < 4; ++j) {
                if (i + g + j * 4 < d) {
                    s[0] += bflo(v[j].x); s[1] += bfhi(v[j].x);
                    s[2] += bflo(v[j].y); s[3] += bfhi(v[j].y);
                    s[4] += bflo(v[j].z); s[5] += bfhi(v[j].z);
                    s[6] += bflo(v[j].w); s[7] += bfhi(v[j].w);
                }
            }
        }
        #pragma unroll
        for (int r = 0; r < 8; ++r) {
            s[r] += __shfl_xor(s[r], 16);
            s[r] += __shfl_xor(s[r], 32);
        }
    }
    if (valid) {
        if (lane < 16) {
            #pragma unroll
            for (int r = 0; r < 8; ++r) xbuf[w][lane * 8 + r] = s[r];
        }
        float invd = 1.0f / (float)(d > 1 ? d : 1);
        unsigned int vr = *(const unsigned int*)&Pz[(size_t)n * FC + lane * 2];
        float x0 = xbuf[w][2 * lane] * invd + bl[2 * lane] + bflo(vr);
        float x1 = xbuf[w][2 * lane + 1] * invd + bl[2 * lane + 1] + bfhi(vr);
        x0 = (x0 >= 0.f) ? x0 : 0.01f * x0;
        x1 = (x1 >= 0.f) ? x1 : 0.01f * x1;
        xbuf[w][2 * lane] = x0;
        xbuf[w][2 * lane + 1] = x1;
        if (lane < ADD_CH) xbuf[w][FC + lane] = addf[(size_t)n * ADD_CH + lane];
        if (lane < MID) {
            float h = b1[lane];
            #pragma unroll 4
            for (int k = 0; k < XCH; ++k) h += W1s[k][lane] * xbuf[w][k];
            h = fmaxf(h, 0.0f);
            h = gamma[lane] * (h - rmean[lane]) * rsqrtf(rvar[lane] + 1e-5f) + beta[lane];
            hbuf[w][lane] = h;
        }
        if (lane < OUT_CH) {
            float o = b2[lane];
            #pragma unroll
            for (int j = 0; j < MID; ++j) o += W2[lane * MID + j] * hbuf[w][j];
            out[(size_t)n * OUT_CH + lane] = o;
        }
    }
}

// ---------------- launch ----------------

extern "C" void kernel_launch(void* const* d_in, const int* in_sizes, int n_in,
                              void* d_out, int out_size, void* d_ws, size_t ws_size,
                              hipStream_t stream) {
    const float* features = (const float*)d_in[0];
    const int*   edges    = (const int*)d_in[1];
    const float* addf     = (const float*)d_in[4];
    const float* Wl       = (const float*)d_in[5];
    const float* bl       = (const float*)d_in[6];
    const float* Wr       = (const float*)d_in[7];
    const float* W1       = (const float*)d_in[8];
    const float* b1       = (const float*)d_in[9];
    const float* W2       = (const float*)d_in[10];
    const float* b2       = (const float*)d_in[11];
    const float* gamma    = (const float*)d_in[12];
    const float* beta     = (const float*)d_in[13];
    const float* rmean    = (const float*)d_in[14];
    const float* rvar     = (const float*)d_in[15];
    float* out = (float*)d_out;

    char* ws = (char*)d_ws;
    size_t off = 0;
    ushort* Py = (ushort*)(ws + off);     off += (size_t)N_NODES * FC * 2;            // 6.4 MB
    ushort* Pz = (ushort*)(ws + off);     off += (size_t)N_NODES * FC * 2;            // 6.4 MB
    ushort* Wpk = (ushort*)(ws + off);    off += (size_t)32 * 16 * 64 * 16;           // 512 KB
    int* cursor = (int*)(ws + off);       off += (size_t)N_NODES * CSTRIDE * 4;       // 1.6 MB
    int* col = (int*)(ws + off);          off += (size_t)N_NODES * MAXDEG * 4;        // 6.4 MB

    prep<<<WSWZ_B + ZERO_B, 512, 0, stream>>>(Wl, Wr, Wpk, cursor);

    gemm_build<<<GEMM_B + BUILD_B, 256, 0, stream>>>(features, Wpk, Py, Pz,
                                                     edges, cursor, col);

    fused_tail<<<(N_NODES + 7) / 8, 512, 0, stream>>>(Py, Pz, cursor, col, addf, bl,
                                                      W1, b1, W2, b2, gamma, beta,
                                                      rmean, rvar, out);
}

// Round 10
// 270.437 us; speedup vs baseline: 1.1809x; 1.1809x over previous
//
#include <hip/hip_runtime.h>

#define N_NODES 25000
#define N_EDGES 400000
#define IN_CH 1024
#define FC 128
#define ADD_CH 20
#define XCH 148   // FC + ADD
#define MID 37
#define OUT_CH 3
#define MAXDEG 64
#define CSTRIDE 16   // cursor padded to one counter per 64B line

typedef short bf16x8 __attribute__((ext_vector_type(8)));
typedef float f32x4 __attribute__((ext_vector_type(4)));
typedef unsigned int u32x4 __attribute__((ext_vector_type(4)));

__device__ __forceinline__ float bflo(unsigned int v) {
    return __builtin_bit_cast(float, v << 16);
}
__device__ __forceinline__ float bfhi(unsigned int v) {
    return __builtin_bit_cast(float, v & 0xffff0000u);
}
// pack 2 f32 -> 2 bf16 (RNE), single VALU op
__device__ __forceinline__ unsigned int cvtpk(float a, float b) {
    unsigned int r;
    asm("v_cvt_pk_bf16_f32 %0, %1, %2" : "=v"(r) : "v"(a), "v"(b));
    return r;
}

// async 16B global->LDS DMA (counts in vmcnt)
__device__ __forceinline__ void gload16(const void* g, void* l) {
    __builtin_amdgcn_global_load_lds(
        (const __attribute__((address_space(1))) unsigned int*)g,
        (__attribute__((address_space(3))) unsigned int*)l,
        16, 0, 0);
}

// ---------------- prep: W swizzle + cursor zero (one dispatch) --------------
// Wpk layout: [kt(32)][chgrp(16)][lane(64)] x 16B; unit (kt,chgrp) lane (q,l15)
// holds W[chgrp*16+l15][kt*32+q*8 .. +8] as bf16x8. 512 KB, L2-resident.
#define WSWZ_B 16
#define ZERO_B 49   // 49*512 >= 25000

__global__ __launch_bounds__(512) void prep(const float* __restrict__ Wl,
                                            const float* __restrict__ Wr,
                                            ushort* __restrict__ Wpk,
                                            int* __restrict__ cursor) {
    int b = blockIdx.x, t = threadIdx.x;
    if (b < WSWZ_B) {
        int w = t >> 6, lane = t & 63, l15 = lane & 15, q8 = (lane >> 4) * 8;
        int ch = b * 16 + l15;
        const float* src = (ch < FC) ? (Wl + (size_t)ch * IN_CH)
                                     : (Wr + (size_t)(ch - FC) * IN_CH);
        #pragma unroll
        for (int j = 0; j < 4; ++j) {
            int kt = w * 4 + j;
            float4 lo = *(const float4*)(src + kt * 32 + q8);
            float4 hi = *(const float4*)(src + kt * 32 + q8 + 4);
            uint4 pk;
            pk.x = cvtpk(lo.x, lo.y); pk.y = cvtpk(lo.z, lo.w);
            pk.z = cvtpk(hi.x, hi.y); pk.w = cvtpk(hi.z, hi.w);
            ((uint4*)Wpk)[((size_t)kt * 16 + b) * 64 + lane] = pk;
        }
    } else {
        int i = (b - WSWZ_B) * 512 + t;
        if (i < N_NODES) {
            uint4 z = {0, 0, 0, 0};
            uint4* dst = (uint4*)(cursor + (size_t)i * CSTRIDE);
            dst[0] = z; dst[1] = z; dst[2] = z; dst[3] = z;
        }
    }
}

// ---------------- hetero: hybrid GEMM (A via LDS, W via asm-pinned regs) ----
// R9 evidence: hipcc collapses ANY source-level register prefetch (VGPR=40).
// R8 evidence: LDS path works but W-through-LDS doubles LDS traffic (176KB
// /chunk/CU) and couples W to the barrier convoy. Hybrid:
//   * A (shared by all 8 waves) -> LDS, depth-3, counted vmcnt (R8 recipe),
//     1 gload16/thread/chunk (8KB/block/chunk).
//   * W (private per wave after 32ch x 64n remap) -> registers via inline-asm
//     global_load_dwordx4, explicit named 3-bank rotation. asm volatile +
//     ordered s_waitcnt = compiler CANNOT collapse the queue.
//   Wave w: ch [w*32,(w+1)*32) x all 64 nodes -> acc[2][4]; 8 MFMA/chunk.
//   Per chunk/wave: 2 W-loads + 8 ds_read_b128 + 16 cvtpk + 8 MFMA.
//   vmcnt: 3 ops/chunk/thread (1 gload + 2 W); steady wait vmcnt(6).
// Build rides along unchanged (4-edge ILP chains).
#define GEMM_B 391    // ceil(25000/64)
#define BUILD_B 196   // ceil(400000/2048)

__global__ __launch_bounds__(512, 4) void gemm_build(const float* __restrict__ A,
                                                     const ushort* __restrict__ Wpk,
                                                     ushort* __restrict__ Py,
                                                     ushort* __restrict__ Pz,
                                                     const int* __restrict__ edges,
                                                     int* __restrict__ cursor,
                                                     int* __restrict__ col) {
    __shared__ uint4 LDS[3][512];    // A only: 3 bufs x 8 KB = 24 KB
    int b = blockIdx.x, t = threadIdx.x;
    if (b >= GEMM_B) {
        int base = (b - GEMM_B) * 2048 + t;
        int src[4], dst[4], pos[4];
        #pragma unroll
        for (int k = 0; k < 4; ++k) {
            int e = base + k * 512;
            bool v = (e < N_EDGES);
            dst[k] = v ? edges[N_EDGES + e] : 0;
            src[k] = v ? edges[e] : 0;
        }
        #pragma unroll
        for (int k = 0; k < 4; ++k) {
            int e = base + k * 512;
            if (e < N_EDGES)
                pos[k] = atomicAdd(&cursor[(size_t)dst[k] * CSTRIDE], 1);
        }
        #pragma unroll
        for (int k = 0; k < 4; ++k) {
            int e = base + k * 512;
            if (e < N_EDGES && pos[k] < MAXDEG)
                col[dst[k] * MAXDEG + pos[k]] = src[k];
        }
        return;
    }
    int m0 = b * 64;
    int w = t >> 6, lane = t & 63;
    int l15 = lane & 15, q = lane >> 4;
    int tb = t & ~63;                 // wave-uniform LDS slot base

    // A staging source: slot t = (g, h, lane); node = m0+g*16+l15,
    // float offset = q*8 + h*4 (+ c*32 per chunk)
    int ga = t >> 7, hq = (t >> 6) & 1;
    int nodeA = m0 + ga * 16 + l15;
    if (nodeA >= N_NODES) nodeA = N_NODES - 1;
    const float* Asrc = A + (size_t)nodeA * IN_CH + q * 8 + hq * 4;

    // W byte offset for this wave's chgrp pair (2w, 2w+1); +16384/chunk
    unsigned voff0 = (unsigned)(w * 128 + lane) * 16u;

    f32x4 acc[2][4] = {};
    u32x4 wA0, wA1, wB0, wB1, wC0, wC1;

    #define ISSUE_W(R0, R1, vo)                                                   \
        asm volatile("global_load_dwordx4 %0, %2, %3\n\t"                         \
                     "global_load_dwordx4 %1, %2, %3 offset:1024"                 \
                     : "=&v"(R0), "=&v"(R1) : "v"(vo), "s"(Wpk) : "memory");

    // prologue: chunks 0 -> (LDS0, bankA), 1 -> (LDS1, bankB); 6 ops in flight
    gload16(Asrc, &LDS[0][tb]);
    ISSUE_W(wA0, wA1, voff0)
    gload16(Asrc + 32, &LDS[1][tb]);
    { unsigned vo = voff0 + 16384u; ISSUE_W(wB0, wB1, vo) }

    #define COMPUTE(W0r, W1r, cb)                                                 \
    {                                                                             \
        bf16x8 wf0 = __builtin_bit_cast(bf16x8, W0r);                             \
        bf16x8 wf1 = __builtin_bit_cast(bf16x8, W1r);                             \
        _Pragma("unroll")                                                         \
        for (int g = 0; g < 4; ++g) {                                             \
            f32x4 lo = *(const f32x4*)&LDS[cb][g * 128 + lane];                   \
            f32x4 hi = *(const f32x4*)&LDS[cb][g * 128 + 64 + lane];              \
            uint4 pk_;                                                            \
            pk_.x = cvtpk(lo[0], lo[1]); pk_.y = cvtpk(lo[2], lo[3]);             \
            pk_.z = cvtpk(hi[0], hi[1]); pk_.w = cvtpk(hi[2], hi[3]);             \
            bf16x8 af = __builtin_bit_cast(bf16x8, pk_);                          \
            acc[0][g] = __builtin_amdgcn_mfma_f32_16x16x32_bf16(wf0, af, acc[0][g], 0, 0, 0); \
            acc[1][g] = __builtin_amdgcn_mfma_f32_16x16x32_bf16(wf1, af, acc[1][g], 0, 0, 0); \
        }                                                                         \
    }

    #define STEP(c, WS0, WS1, WC0, WC1, SBUF, CBUF)                               \
    {                                                                             \
        gload16(Asrc + (size_t)((c) + 2) * 32, &LDS[SBUF][tb]);                   \
        unsigned vo = voff0 + (unsigned)((c) + 2) * 16384u;                       \
        ISSUE_W(WS0, WS1, vo)                                                     \
        asm volatile("s_waitcnt vmcnt(6)" ::: "memory");                          \
        __builtin_amdgcn_sched_barrier(0);                                        \
        __builtin_amdgcn_s_barrier();                                             \
        __builtin_amdgcn_sched_barrier(0);                                        \
        COMPUTE(WC0, WC1, CBUF);                                                  \
        __builtin_amdgcn_s_barrier();                                             \
        __builtin_amdgcn_sched_barrier(0);                                        \
    }

    for (int cc = 0; cc < 30; cc += 3) {
        STEP(cc,     wC0, wC1, wA0, wA1, 2, 0)
        STEP(cc + 1, wA0, wA1, wB0, wB1, 0, 1)
        STEP(cc + 2, wB0, wB1, wC0, wC1, 1, 2)
    }
    // chunk 30 (bankA/LDS0): only chunk 31's 3 ops may remain in flight
    asm volatile("s_waitcnt vmcnt(3)" ::: "memory");
    __builtin_amdgcn_sched_barrier(0);
    __builtin_amdgcn_s_barrier();
    __builtin_amdgcn_sched_barrier(0);
    COMPUTE(wA0, wA1, 0);
    // chunk 31 (bankB/LDS1): drain fully
    asm volatile("s_waitcnt vmcnt(0)" ::: "memory");
    __builtin_amdgcn_sched_barrier(0);
    __builtin_amdgcn_s_barrier();
    __builtin_amdgcn_sched_barrier(0);
    COMPUTE(wB0, wB1, 1);
    #undef STEP
    #undef COMPUTE
    #undef ISSUE_W

    // D layout: ch = w*32 + cf*16 + q*4 + reg, node = m0 + g*16 + l15
    #pragma unroll
    for (int g = 0; g < 4; ++g) {
        int node = m0 + g * 16 + l15;
        if (node < N_NODES) {
            ushort* base = (w < 4) ? (Py + (size_t)node * FC + w * 32 + q * 4)
                                   : (Pz + (size_t)node * FC + (w - 4) * 32 + q * 4);
            #pragma unroll
            for (int cf = 0; cf < 2; ++cf) {
                f32x4 v = acc[cf][g];
                uint2 pk;
                pk.x = cvtpk(v[0], v[1]);
                pk.y = cvtpk(v[2], v[3]);
                *(uint2*)(base + cf * 16) = pk;
            }
        }
    }
}

// ---------------- fused gather + SAGE combine + MLP tail (8 nodes/block) ----
__global__ __launch_bounds__(512) void fused_tail(const ushort* __restrict__ Py,
                                                  const ushort* __restrict__ Pz,
                                                  const int* __restrict__ deg,
                                                  const int* __restrict__ col,
                                                  const float* __restrict__ addf,
                                                  const float* __restrict__ bl,
                                                  const float* __restrict__ W1,
                                                  const float* __restrict__ b1,
                                                  const float* __restrict__ W2,
                                                  const float* __restrict__ b2,
                                                  const float* __restrict__ gamma,
                                                  const float* __restrict__ beta,
                                                  const float* __restrict__ rmean,
                                                  const float* __restrict__ rvar,
                                                  float* __restrict__ out) {
    __shared__ float W1s[XCH][MID + 3];
    __shared__ float xbuf[8][XCH + 4];
    __shared__ float hbuf[8][MID + 3];
    int t = threadIdx.x;
    for (int idx = t; idx < MID * XCH; idx += 512) {
        int j = idx / XCH, k = idx - j * XCH;
        W1s[k][j] = W1[idx];
    }
    __syncthreads();
    int w = t >> 6, lane = t & 63;
    int n = blockIdx.x * 8 + w;
    bool valid = (n < N_NODES);
    int d = valid ? deg[(size_t)n * CSTRIDE] : 0;
    if (d > MAXDEG) d = MAXDEG;
    int g = lane >> 4, c16 = lane & 15;
    float s[8] = {0.f, 0.f, 0.f, 0.f, 0.f, 0.f, 0.f, 0.f};
    if (d > 0) {
        int cidx = col[n * MAXDEG + (lane < d ? lane : 0)];
        for (int i = 0; i < d; i += 16) {
            int e[4];
            uint4 v[4];
            #pragma unroll
            for (int j = 0; j < 4; ++j) {
                int ee = i + g + j * 4;
                e[j] = __shfl(cidx, (ee < d) ? ee : 0);
            }
            #pragma unroll
            for (int j = 0; j < 4; ++j)
                v[j] = *(const uint4*)&Py[(size_t)e[j] * FC + c16 * 8];
            #pragma unroll
            for (int j = 0; j < 4; ++j) {
                if (i + g + j * 4 < d) {
                    s[0] += bflo(v[j].x); s[1] += bfhi(v[j].x);
                    s[2] += bflo(v[j].y); s[3] += bfhi(v[j].y);
                    s[4] += bflo(v[j].z); s[5] += bfhi(v[j].z);
                    s[6] += bflo(v[j].w); s[7] += bfhi(v[j].w);
                }
            }
        }
        #pragma unroll
        for (int r = 0; r < 8; ++r) {
            s[r] += __shfl_xor(s[r], 16);
            s[r] += __shfl_xor(s[r], 32);
        }
    }
    if (valid) {
        if (lane < 16) {
            #pragma unroll
            for (int r = 0; r < 8; ++r) xbuf[w][lane * 8 + r] = s[r];
        }
        float invd = 1.0f / (float)(d > 1 ? d : 1);
        unsigned int vr = *(const unsigned int*)&Pz[(size_t)n * FC + lane * 2];
        float x0 = xbuf[w][2 * lane] * invd + bl[2 * lane] + bflo(vr);
        float x1 = xbuf[w][2 * lane + 1] * invd + bl[2 * lane + 1] + bfhi(vr);
        x0 = (x0 >= 0.f) ? x0 : 0.01f * x0;
        x1 = (x1 >= 0.f) ? x1 : 0.01f * x1;
        xbuf[w][2 * lane] = x0;
        xbuf[w][2 * lane + 1] = x1;
        if (lane < ADD_CH) xbuf[w][FC + lane] = addf[(size_t)n * ADD_CH + lane];
        if (lane < MID) {
            float h = b1[lane];
            #pragma unroll 4
            for (int k = 0; k < XCH; ++k) h += W1s[k][lane] * xbuf[w][k];
            h = fmaxf(h, 0.0f);
            h = gamma[lane] * (h - rmean[lane]) * rsqrtf(rvar[lane] + 1e-5f) + beta[lane];
            hbuf[w][lane] = h;
        }
        if (lane < OUT_CH) {
            float o = b2[lane];
            #pragma unroll
            for (int j = 0; j < MID; ++j) o += W2[lane * MID + j] * hbuf[w][j];
            out[(size_t)n * OUT_CH + lane] = o;
        }
    }
}

// ---------------- launch ----------------

extern "C" void kernel_launch(void* const* d_in, const int* in_sizes, int n_in,
                              void* d_out, int out_size, void* d_ws, size_t ws_size,
                              hipStream_t stream) {
    const float* features = (const float*)d_in[0];
    const int*   edges    = (const int*)d_in[1];
    const float* addf     = (const float*)d_in[4];
    const float* Wl       = (const float*)d_in[5];
    const float* bl       = (const float*)d_in[6];
    const float* Wr       = (const float*)d_in[7];
    const float* W1       = (const float*)d_in[8];
    const float* b1       = (const float*)d_in[9];
    const float* W2       = (const float*)d_in[10];
    const float* b2       = (const float*)d_in[11];
    const float* gamma    = (const float*)d_in[12];
    const float* beta     = (const float*)d_in[13];
    const float* rmean    = (const float*)d_in[14];
    const float* rvar     = (const float*)d_in[15];
    float* out = (float*)d_out;

    char* ws = (char*)d_ws;
    size_t off = 0;
    ushort* Py = (ushort*)(ws + off);     off += (size_t)N_NODES * FC * 2;            // 6.4 MB
    ushort* Pz = (ushort*)(ws + off);     off += (size_t)N_NODES * FC * 2;            // 6.4 MB
    ushort* Wpk = (ushort*)(ws + off);    off += (size_t)32 * 16 * 64 * 16;           // 512 KB
    int* cursor = (int*)(ws + off);       off += (size_t)N_NODES * CSTRIDE * 4;       // 1.6 MB
    int* col = (int*)(ws + off);          off += (size_t)N_NODES * MAXDEG * 4;        // 6.4 MB

    prep<<<WSWZ_B + ZERO_B, 512, 0, stream>>>(Wl, Wr, Wpk, cursor);

    gemm_build<<<GEMM_B + BUILD_B, 512, 0, stream>>>(features, Wpk, Py, Pz,
                                                     edges, cursor, col);

    fused_tail<<<(N_NODES + 7) / 8, 512, 0, stream>>>(Py, Pz, cursor, col, addf, bl,
                                                      W1, b1, W2, b2, gamma, beta,
                                                      rmean, rvar, out);
}